// Round 24
// baseline (131.073 us; speedup 1.0000x reference)
//
#include <hip/hip_runtime.h>

#define DIM     256
#define HW      1024
#define N_ROWS  65536
#define MARGIN  0.125f
#define MARGIN3 0.1875f

#define OUT_Q_OFF    16777216
#define OUT_LOSS_OFF 16842752

// ws: floats [0,512) c2 ; [512,2560) dist partials(2048) ; [2560,4608) x2 partials(2048)
// ints: [4608] full cnt ; [4609] pair cnt ; [5120,21504) full list ; [21504,119808) pair list (x3)
// bytes: [786432,1048576) lut fp16 fragment-linear (256KB)
#define WS_DIST    512
#define WS_X2      2560
#define WS_CNTF_I  4608
#define WS_CNTP_I  4609
#define WS_LISTF_I 5120
#define WS_LISTP_I 21504
#define CAP_F      16384
#define CAP_P      32768
#define WS_LUTH_B  786432

#define VQ_LDS 131072   // B half: 128 chunks x 1KB

typedef _Float16 half8v __attribute__((ext_vector_type(8)));
typedef float floatx4 __attribute__((ext_vector_type(4)));

#define GLOAD_LDS16(gaddr, laddr) \
    __builtin_amdgcn_global_load_lds((const __attribute__((address_space(1))) unsigned int*)(gaddr), \
                                     (__attribute__((address_space(3))) unsigned int*)(laddr), 16, 0, 0)

__global__ void c2_kernel(const float* __restrict__ lut, float* __restrict__ ws) {
    if (threadIdx.x == 0) { ((int*)ws)[WS_CNTF_I] = 0; ((int*)ws)[WS_CNTP_I] = 0; }
    int t = threadIdx.x;
    for (int k = t; k < 512; k += 256) {
        const float4* row = (const float4*)(lut + (size_t)k * DIM);
        float s = 0.f;
        #pragma unroll 8
        for (int i = 0; i < DIM / 4; ++i) {
            float4 v = row[i];
            s += v.x * v.x + v.y * v.y + v.z * v.z + v.w * v.w;
        }
        ws[k] = s;
    }
}

// lut -> fp16 fragment-linear: chunk(dc*32+ctu)*1KB + lane*16B (R14-proven layout)
__global__ void lutprep_kernel(const float* __restrict__ lut, float* __restrict__ ws) {
    int g = blockIdx.x * 256 + threadIdx.x;    // 0..16383
    int lane = g & 63;
    int ctu  = (g >> 6) & 31;
    int dcg  = g >> 11;
    int code = ctu * 16 + (lane & 15);
    int d0   = dcg * 32 + (lane >> 4) * 8;
    const float* src = lut + (size_t)code * DIM + d0;
    half8v h;
    #pragma unroll
    for (int j = 0; j < 8; ++j) h[j] = (_Float16)src[j];
    char* dst = (char*)ws + WS_LUTH_B + (size_t)(dcg * 32 + ctu) * 1024 + lane * 16;
    *(half8v*)dst = h;
}

// merge triple (v1,i1,v2,i2,v3) <- union with (w1,j1,w2,j2,w3)  [R15-proven]
#define MERGE_TRIPLE(v1,i1,v2,i2,v3, w1,j1,w2,j2,w3)                          \
    {                                                                         \
        float a1,a2,a3,b1v,b2v; int a1i,a2i,b1i,b2i;                          \
        bool bf = (w1 < v1) || (w1 == v1 && j1 < i1);                         \
        if (bf) { a1=w1;a1i=j1;a2=w2;a2i=j2;a3=w3; b1v=v1;b1i=i1;b2v=v2;b2i=i2; } \
        else    { a1=v1;a1i=i1;a2=v2;a2i=i2;a3=v3; b1v=w1;b1i=j1;b2v=w2;b2i=j2; } \
        bool sa = (a2 < b1v) || (a2 == b1v && a2i < b1i);                     \
        v1 = a1; i1 = a1i;                                                    \
        if (sa) { v2 = a2; i2 = a2i; v3 = fminf(a3, b1v); }                   \
        else    { v2 = b1v; i2 = b1i; v3 = fminf(a2, b2v); }                  \
    }

__global__ __launch_bounds__(512, 1) void vq_kernel(const float* __restrict__ x,
                                                    const float* __restrict__ lut,
                                                    float* __restrict__ out,
                                                    float* __restrict__ ws) {
    extern __shared__ char smem[];   // [0,131072): B half, chunks (dc*16+cl)*1024 + lane*16
    const char* luth = (const char*)ws + WS_LUTH_B;

    const int tid  = threadIdx.x;
    const int blk  = blockIdx.x;
    const int wave = tid >> 6;
    const int lane = tid & 63;
    const int l15  = lane & 15;
    const int l4   = lane >> 4;

    const int n0w = blk * 256 + wave * 32;   // this wave's 32 rows
    const int b   = n0w >> 10;
    const int hw0 = n0w & 1023;
    const float* xb = x + (size_t)b * (DIM * HW) + hw0;

    // ---- A frags to registers ONCE (proven fragment layout: row=t*16+l15, d=dc*32+l4*8+j) ----
    half8v a[2][8];
    float x2local = 0.f;
    #pragma unroll
    for (int t = 0; t < 2; ++t) {
        #pragma unroll
        for (int dc = 0; dc < 8; ++dc) {
            const float* src = xb + (size_t)(dc * 32 + l4 * 8) * HW + t * 16 + l15;
            half8v hh;
            #pragma unroll
            for (int j = 0; j < 8; ++j) {
                float v = src[(size_t)j * HW];
                x2local = fmaf(v, v, x2local);
                hh[j] = (_Float16)v;
            }
            a[t][dc] = hh;
        }
    }

    // running top-3 per (t, r)
    float v1[2][4], v2[2][4], v3[2][4]; int i1[2][4], i2[2][4];
    #pragma unroll
    for (int t = 0; t < 2; ++t)
        #pragma unroll
        for (int r = 0; r < 4; ++r) { v1[t][r]=3.4e38f; v2[t][r]=3.4e38f; v3[t][r]=3.4e38f; i1[t][r]=0; i2[t][r]=0; }

    // ---- two passes over code halves; B half resident in LDS ----
    for (int p = 0; p < 2; ++p) {
        // cooperative B-half load: 8192 x 16B via gload_lds
        __syncthreads();   // pass>0: all waves done reading previous half
        #pragma unroll
        for (int i = 0; i < 16; ++i) {
            int idx = i * 512 + tid;
            int ck  = idx >> 6;                       // LDS chunk 0..127
            int sc  = (ck >> 4) * 32 + p * 16 + (ck & 15);  // lutbf chunk
            GLOAD_LDS16(luth + (size_t)sc * 1024 + lane * 16, smem + ck * 1024);
        }
        __syncthreads();   // full drain: B half resident

        // barrier-free inner loop: 16 ctu x {8 ds_read + 16 MFMA + fold}
        for (int cl = 0; cl < 16; ++cl) {
            half8v bh[8];
            #pragma unroll
            for (int dc = 0; dc < 8; ++dc)
                bh[dc] = *(const half8v*)(smem + (size_t)(dc * 16 + cl) * 1024 + lane * 16);
            floatx4 acc0 = (floatx4)0.f, acc1 = (floatx4)0.f;
            #pragma unroll
            for (int dc = 0; dc < 8; ++dc) {
                acc0 = __builtin_amdgcn_mfma_f32_16x16x32_f16(a[0][dc], bh[dc], acc0, 0, 0, 0);
                acc1 = __builtin_amdgcn_mfma_f32_16x16x32_f16(a[1][dc], bh[dc], acc1, 0, 0, 0);
            }
            const int code = (p * 16 + cl) * 16 + l15;
            const float c2v = ws[code];
            #pragma unroll
            for (int r = 0; r < 4; ++r) {
                float d0f = fmaf(-2.f, acc0[r], c2v);
                if (d0f < v1[0][r])      { v3[0][r]=v2[0][r]; v2[0][r]=v1[0][r]; i2[0][r]=i1[0][r]; v1[0][r]=d0f; i1[0][r]=code; }
                else if (d0f < v2[0][r]) { v3[0][r]=v2[0][r]; v2[0][r]=d0f; i2[0][r]=code; }
                else if (d0f < v3[0][r]) { v3[0][r]=d0f; }
                float d1f = fmaf(-2.f, acc1[r], c2v);
                if (d1f < v1[1][r])      { v3[1][r]=v2[1][r]; v2[1][r]=v1[1][r]; i2[1][r]=i1[1][r]; v1[1][r]=d1f; i1[1][r]=code; }
                else if (d1f < v2[1][r]) { v3[1][r]=v2[1][r]; v2[1][r]=d1f; i2[1][r]=code; }
                else if (d1f < v3[1][r]) { v3[1][r]=d1f; }
            }
        }
    }

    // ---- cross-lane top-3 merge over l15 group (leaves result in all lanes) ----
    #pragma unroll
    for (int t = 0; t < 2; ++t) {
        #pragma unroll
        for (int r = 0; r < 4; ++r) {
            #pragma unroll
            for (int off = 1; off < 16; off <<= 1) {
                float w1 = __shfl_xor(v1[t][r], off, 64);
                int   j1 = __shfl_xor(i1[t][r], off, 64);
                float w2 = __shfl_xor(v2[t][r], off, 64);
                int   j2 = __shfl_xor(i2[t][r], off, 64);
                float w3 = __shfl_xor(v3[t][r], off, 64);
                MERGE_TRIPLE(v1[t][r], i1[t][r], v2[t][r], i2[t][r], v3[t][r], w1, j1, w2, j2, w3);
            }
        }
    }

    // ---- q write, flags, dist partial (holder lanes l15==0; rows t*16 + l4*4 + r) ----
    float dist_part = 0.f;
    if (l15 == 0) {
        #pragma unroll
        for (int t = 0; t < 2; ++t) {
            #pragma unroll
            for (int r = 0; r < 4; ++r) {
                int row = t * 16 + l4 * 4 + r;
                int n1 = i1[t][r];
                out[OUT_Q_OFF + n0w + row] = (float)n1;
                float m1 = v1[t][r], m2 = v2[t][r], m3 = v3[t][r];
                if (m2 - m1 <= MARGIN) {
                    if (m3 - m1 > MARGIN3) {
                        int idx = atomicAdd((int*)ws + WS_CNTP_I, 1);
                        if (idx < CAP_P) {
                            ((int*)ws)[WS_LISTP_I + idx * 3 + 0] = n0w + row;
                            ((int*)ws)[WS_LISTP_I + idx * 3 + 1] = n1;
                            ((int*)ws)[WS_LISTP_I + idx * 3 + 2] = i2[t][r];
                        }
                    } else {
                        int idx = atomicAdd((int*)ws + WS_CNTF_I, 1);
                        if (idx < CAP_F) ((int*)ws)[WS_LISTF_I + idx] = n0w + row;
                    }
                }
                dist_part += m1;
            }
        }
    }
    float dv = dist_part;
    #pragma unroll
    for (int off = 32; off; off >>= 1) dv += __shfl_down(dv, off, 64);
    if (lane == 0) ws[WS_DIST + blk * 8 + wave] = dv;
    float xv = x2local;
    #pragma unroll
    for (int off = 32; off; off >>= 1) xv += __shfl_down(xv, off, 64);
    if (lane == 0) ws[WS_X2 + blk * 8 + wave] = xv;

    // ---- x_e write: lane covers rows 4h..4h+3 (h=lane&7), d=(g+8p)*8+j (g=lane>>3) ----
    {
        const int h = lane & 7;
        const int g = lane >> 3;
        int qs[4];
        #pragma unroll
        for (int r = 0; r < 4; ++r) {
            // q for row 4h+r is held by lanes with l4 == (h&3), t == h>>2 (all l15 have it)
            int qa = __shfl(i1[0][r], (h & 3) * 16, 64);
            int qb = __shfl(i1[1][r], (h & 3) * 16, 64);
            qs[r] = (h >> 2) ? qb : qa;
        }
        float* ob = out + (size_t)b * (DIM * HW) + hw0 + 4 * h;
        #pragma unroll
        for (int pd = 0; pd < 4; ++pd) {
            #pragma unroll
            for (int j = 0; j < 8; ++j) {
                int d = (g + 8 * pd) * 8 + j;
                float4 c;
                float* cp = (float*)&c;
                #pragma unroll
                for (int r = 0; r < 4; ++r) cp[r] = lut[(size_t)qs[r] * DIM + d];
                *(float4*)(ob + (size_t)d * HW) = c;
            }
        }
    }
}

// recheck: ONE BLOCK PER FLAGGED ROW (R21-proven; cooperative staging)
__global__ void recheck_kernel(const float* __restrict__ x, const float* __restrict__ lut,
                               float* __restrict__ out, const float* __restrict__ ws) {
    __shared__ float xrow[DIM];
    __shared__ float carow[DIM];
    __shared__ float cbrow[DIM];
    __shared__ float frv[256];
    __shared__ int   fri[256];
    __shared__ int   qq;
    const int tid = threadIdx.x;

    int cntp = ((const int*)ws)[WS_CNTP_I];
    if (cntp > CAP_P) cntp = CAP_P;
    const int* lp = (const int*)ws + WS_LISTP_I;
    for (int e = blockIdx.x; e < cntp; e += gridDim.x) {
        const int row = lp[e * 3 + 0];
        const int ia  = lp[e * 3 + 1];
        const int ib  = lp[e * 3 + 2];
        const int b = row >> 10, hw = row & 1023;
        xrow[tid]  = x[(size_t)b * (DIM * HW) + (size_t)tid * HW + hw];
        carow[tid] = lut[(size_t)ia * DIM + tid];
        cbrow[tid] = lut[(size_t)ib * DIM + tid];
        __syncthreads();
        if (tid == 0) {
            float dota = 0.f, dotb = 0.f;
            for (int d = 0; d < DIM; ++d) {
                dota = fmaf(xrow[d], carow[d], dota);
                dotb = fmaf(xrow[d], cbrow[d], dotb);
            }
            float da = fmaf(-2.f, dota, ws[ia]);
            float db = fmaf(-2.f, dotb, ws[ib]);
            int q;
            if (da < db) q = ia;
            else if (db < da) q = ib;
            else q = (ia < ib) ? ia : ib;
            qq = q;
            out[OUT_Q_OFF + row] = (float)q;
        }
        __syncthreads();
        const int q = qq;
        out[(size_t)b * (DIM * HW) + (size_t)tid * HW + hw] = lut[(size_t)q * DIM + tid];
        __syncthreads();
    }

    int cntf = ((const int*)ws)[WS_CNTF_I];
    if (cntf > CAP_F) cntf = CAP_F;
    const int* lf = (const int*)ws + WS_LISTF_I;
    for (int e = blockIdx.x; e < cntf; e += gridDim.x) {
        const int row = lf[e];
        const int b = row >> 10, hw = row & 1023;
        xrow[tid] = x[(size_t)b * (DIM * HW) + (size_t)tid * HW + hw];
        __syncthreads();
        float bv = 3.4e38f; int bi = 0;
        #pragma unroll
        for (int k2 = 0; k2 < 2; ++k2) {
            int k = tid + k2 * 256;
            const float* cr = lut + (size_t)k * DIM;
            float dot = 0.f;
            for (int d = 0; d < DIM; ++d) dot = fmaf(xrow[d], cr[d], dot);
            float dist = fmaf(-2.f, dot, ws[k]);
            if (dist < bv || (dist == bv && k < bi)) { bv = dist; bi = k; }
        }
        frv[tid] = bv; fri[tid] = bi;
        __syncthreads();
        for (int s = 128; s; s >>= 1) {
            if (tid < s) {
                float ov = frv[tid + s]; int oi = fri[tid + s];
                if (ov < frv[tid] || (ov == frv[tid] && oi < fri[tid])) {
                    frv[tid] = ov; fri[tid] = oi;
                }
            }
            __syncthreads();
        }
        const int q = fri[0];
        if (tid == 0) out[OUT_Q_OFF + row] = (float)q;
        out[(size_t)b * (DIM * HW) + (size_t)tid * HW + hw] = lut[(size_t)q * DIM + tid];
        __syncthreads();
    }
}

__global__ void loss_kernel(float* __restrict__ out, const float* __restrict__ ws) {
    __shared__ float wsum[4];
    int tid = threadIdx.x;
    float s = 0.f;
    for (int i = tid; i < 4096; i += 256) s += ws[WS_DIST + i];   // dist[512,2560) + x2[2560,4608)
    #pragma unroll
    for (int off = 32; off; off >>= 1) s += __shfl_down(s, off, 64);
    if ((tid & 63) == 0) wsum[tid >> 6] = s;
    __syncthreads();
    if (tid == 0) {
        float total = wsum[0] + wsum[1] + wsum[2] + wsum[3];
        out[OUT_LOSS_OFF] = total * (1.25f / 16777216.f);
    }
}

extern "C" void kernel_launch(void* const* d_in, const int* in_sizes, int n_in,
                              void* d_out, int out_size, void* d_ws, size_t ws_size,
                              hipStream_t stream) {
    const float* x   = (const float*)d_in[0];
    const float* lut = (const float*)d_in[1];
    float* out = (float*)d_out;
    float* ws  = (float*)d_ws;

    (void)hipFuncSetAttribute((const void*)vq_kernel,
                              hipFuncAttributeMaxDynamicSharedMemorySize, VQ_LDS);

    c2_kernel<<<1, 256, 0, stream>>>(lut, ws);
    lutprep_kernel<<<64, 256, 0, stream>>>(lut, ws);
    vq_kernel<<<256, 512, VQ_LDS, stream>>>(x, lut, out, ws);
    recheck_kernel<<<2048, 256, 0, stream>>>(x, lut, out, ws);
    loss_kernel<<<1, 256, 0, stream>>>(out, ws);
}